// Round 6
// baseline (28.859 us; speedup 1.0000x reference)
//
#include <hip/hip_runtime.h>
#include <math.h>

#define IN_DIMS 128
#define OUT_PER_B (IN_DIMS * 9)

// Block = 512 threads = TWO batch elements processed IN PARALLEL (not serialized
// like the failed R4 EPB variant: all 8 streaming loads are issued upfront, two
// independent accumulate/reduce trees, one barrier pair amortized over both).
// t -> c = t>>2 (channel), s = t&3 (quarter). Load k: float4 at byte offset
// 16*s + 64*k of channel c => lanes 4c..4c+3 cover whole 64-B lines (1 req/line).
// emb[3a+cc][h][w] = A[a][w]*B[cc][h] exactly (von-Mises x gaussian separable);
// A[a][w]=emb[3a][0][w], B[cc][h]=emb[cc][h][0] scales outputs by emb[0][0][0]>0,
// which cancels in the L2 norm.
__global__ __launch_bounds__(512) void ese_kernel(
        const float* __restrict__ x,     // (B, 128, 8, 8)
        const float* __restrict__ emb,   // (9, 8, 8)
        float* __restrict__ out)         // (B, 1152)
{
    __shared__ float s_out0[OUT_PER_B];  // unnormalized, read back as float4
    __shared__ float s_out1[OUT_PER_B];
    __shared__ float s_red0[8];
    __shared__ float s_red1[8];

    const size_t b0 = (size_t)blockIdx.x * 2;
    const int t = threadIdx.x;
    const int c = t >> 2;            // channel 0..127
    const int s = t & 3;             // quarter 0..3
    const int wb = (s & 1) * 4;      // w-base: 0 or 4
    const int hb = s >> 1;           // h = 2k + hb

    // All 8 streaming loads upfront (two elements, fully independent).
    const float4* __restrict__ xp0 =
        reinterpret_cast<const float4*>(x + (b0 * IN_DIMS + c) * 64);
    const float4* __restrict__ xp1 = xp0 + 2048;   // next element: 128*64/4
    float4 v0[4], v1[4];
#pragma unroll
    for (int k = 0; k < 4; ++k) v0[k] = xp0[s + 4 * k];
#pragma unroll
    for (int k = 0; k < 4; ++k) v1[k] = xp1[s + 4 * k];

    // emb constant slices -> registers (24 dwords, L2-resident).
    float4 sAv[3];
#pragma unroll
    for (int a = 0; a < 3; ++a)
        sAv[a] = *reinterpret_cast<const float4*>(&emb[(3 * a) * 64 + wb]);
    float sBv[3][4];
#pragma unroll
    for (int cc = 0; cc < 3; ++cc)
#pragma unroll
        for (int k = 0; k < 4; ++k)
            sBv[cc][k] = emb[cc * 64 + (2 * k + hb) * 8];

    float acc0[9], acc1[9];
#pragma unroll
    for (int j = 0; j < 9; ++j) { acc0[j] = 0.0f; acc1[j] = 0.0f; }

#pragma unroll
    for (int k = 0; k < 4; ++k) {
#pragma unroll
        for (int a = 0; a < 3; ++a) {
            const float u0 = v0[k].x * sAv[a].x + v0[k].y * sAv[a].y
                           + v0[k].z * sAv[a].z + v0[k].w * sAv[a].w;
            const float u1 = v1[k].x * sAv[a].x + v1[k].y * sAv[a].y
                           + v1[k].z * sAv[a].z + v1[k].w * sAv[a].w;
#pragma unroll
            for (int cc = 0; cc < 3; ++cc) {
                acc0[3 * a + cc] += u0 * sBv[cc][k];
                acc1[3 * a + cc] += u1 * sBv[cc][k];
            }
        }
    }

    // Merge the 4 quarter-lanes of each channel (xor 1,2 are quad_perm DPP).
#pragma unroll
    for (int off = 1; off <= 2; off <<= 1)
#pragma unroll
        for (int j = 0; j < 9; ++j) {
            acc0[j] += __shfl_xor(acc0[j], off, 64);
            acc1[j] += __shfl_xor(acc1[j], off, 64);
        }

    // Stage unnormalized outputs (writer lane s==0; dword stride 9 conflict-free).
    if (s == 0) {
#pragma unroll
        for (int j = 0; j < 9; ++j) {
            s_out0[c * 9 + j] = acc0[j];
            s_out1[c * 9 + j] = acc1[j];
        }
    }

    // Block-wide sum-of-squares partials for both elements.
    float ss0 = 0.0f, ss1 = 0.0f;
#pragma unroll
    for (int j = 0; j < 9; ++j) { ss0 += acc0[j] * acc0[j]; ss1 += acc1[j] * acc1[j]; }
#pragma unroll
    for (int off = 4; off <= 32; off <<= 1) {
        ss0 += __shfl_xor(ss0, off, 64);
        ss1 += __shfl_xor(ss1, off, 64);
    }
    if ((t & 63) == 0) { s_red0[t >> 6] = ss0; s_red1[t >> 6] = ss1; }

    __syncthreads();   // the ONLY barrier

    const float4 p0 = reinterpret_cast<const float4*>(s_red0)[0];
    const float4 p1 = reinterpret_cast<const float4*>(s_red0)[1];
    const float4 q0 = reinterpret_cast<const float4*>(s_red1)[0];
    const float4 q1 = reinterpret_cast<const float4*>(s_red1)[1];
    const float rn0 = 1.0f / sqrtf(((p0.x + p0.y) + (p0.z + p0.w))
                                 + ((p1.x + p1.y) + (p1.z + p1.w)) + 1e-10f);
    const float rn1 = 1.0f / sqrtf(((q0.x + q0.y) + (q0.z + q0.w))
                                 + ((q1.x + q1.y) + (q1.z + q1.w)) + 1e-10f);

    // Normalize at read time; 2 x 288 contiguous float4 stores.
    float4* __restrict__ ob = reinterpret_cast<float4*>(out + b0 * OUT_PER_B);
    if (t < OUT_PER_B / 4) {
        float4 o = reinterpret_cast<const float4*>(s_out0)[t];
        o.x *= rn0; o.y *= rn0; o.z *= rn0; o.w *= rn0;
        ob[t] = o;
        float4 p = reinterpret_cast<const float4*>(s_out1)[t];
        p.x *= rn1; p.y *= rn1; p.z *= rn1; p.w *= rn1;
        ob[OUT_PER_B / 4 + t] = p;
    }
}

extern "C" void kernel_launch(void* const* d_in, const int* in_sizes, int n_in,
                              void* d_out, int out_size, void* d_ws, size_t ws_size,
                              hipStream_t stream) {
    const float* x   = (const float*)d_in[0];
    const float* emb = (const float*)d_in[1];
    float* out       = (float*)d_out;

    const int B = in_sizes[0] / (IN_DIMS * 64);   // 4096
    ese_kernel<<<B / 2, 512, 0, stream>>>(x, emb, out);
}